// Round 1
// baseline (1093.952 us; speedup 1.0000x reference)
//
#include <hip/hip_runtime.h>
#include <stdint.h>

#define D 128
#define KK 256      // stacked K = [mean ; x]
#define TN 64       // nodes per GEMM block

// ---------------------------------------------------------------------------
// edge_index dtype detection: reference asks for int64, but JAX with x64
// disabled silently yields int32. Probe 64 values as int64: packed int32
// pairs give values >= 2^32 (unless hi word == 0, p ~ 1e-5 per element).
__global__ void detect_idx(const void* ei, int* flag, int n_nodes) {
    if (blockIdx.x == 0 && threadIdx.x == 0) {
        const long long* p = (const long long*)ei;
        int is64 = 1;
        for (int i = 0; i < 64; ++i) {
            long long v = p[i];
            if (v < 0 || v >= (long long)n_nodes) { is64 = 0; break; }
        }
        *flag = is64;
    }
}

__global__ void convert_idx(const void* ei, const int* flag,
                            int* src32, int* dst32, int nE) {
    int e = blockIdx.x * blockDim.x + threadIdx.x;
    if (e >= nE) return;
    if (*flag) {
        const long long* p = (const long long*)ei;
        src32[e] = (int)p[e];
        dst32[e] = (int)p[(size_t)nE + e];
    } else {
        const int* p = (const int*)ei;
        src32[e] = p[e];
        dst32[e] = p[nE + e];
    }
}

// ---------------------------------------------------------------------------
// CSR build (by dst), reused across all 3 layers
__global__ void hist_kernel(const int* dst32, int* counts, int nE) {
    int e = blockIdx.x * blockDim.x + threadIdx.x;
    if (e < nE) atomicAdd(&counts[dst32[e]], 1);
}

__global__ void scan1(const int* counts, int* local_inc, int* bsums, int n) {
    __shared__ int s[1024];
    int i = blockIdx.x * 1024 + threadIdx.x;
    int v = (i < n) ? counts[i] : 0;
    s[threadIdx.x] = v;
    __syncthreads();
    for (int off = 1; off < 1024; off <<= 1) {
        int t = 0;
        if ((int)threadIdx.x >= off) t = s[threadIdx.x - off];
        __syncthreads();
        if ((int)threadIdx.x >= off) s[threadIdx.x] += t;
        __syncthreads();
    }
    if (i < n) local_inc[i] = s[threadIdx.x];
    if (threadIdx.x == 1023) bsums[blockIdx.x] = s[1023];
}

__global__ void scan2(int* bsums, int nb) {
    if (blockIdx.x == 0 && threadIdx.x == 0) {
        int run = 0;
        for (int i = 0; i < nb; ++i) { int v = bsums[i]; bsums[i] = run; run += v; }
    }
}

__global__ void scan3(const int* local_inc, const int* counts, const int* bsums,
                      int* offsets, int n, int nE) {
    int i = blockIdx.x * blockDim.x + threadIdx.x;
    if (i < n) offsets[i] = local_inc[i] - counts[i] + bsums[i >> 10];
    if (i == 0) offsets[n] = nE;
}

__global__ void fill_csr(const int* src32, const int* dst32, const int* offsets,
                         int* cursor, int* csr_src, int nE) {
    int e = blockIdx.x * blockDim.x + threadIdx.x;
    if (e < nE) {
        int d = dst32[e];
        int pos = offsets[d] + atomicAdd(&cursor[d], 1);
        csr_src[pos] = src32[e];
    }
}

// ---------------------------------------------------------------------------
// mean aggregation: one wave per node, 64 lanes x float2 = 128-float row
__global__ void agg_mean(const float* __restrict__ act,
                         const int* __restrict__ csr,
                         const int* __restrict__ offs,
                         float* __restrict__ mean, int n) {
    int wid  = (blockIdx.x * blockDim.x + threadIdx.x) >> 6;
    int lane = threadIdx.x & 63;
    if (wid >= n) return;
    int beg = offs[wid], end = offs[wid + 1];
    float ax = 0.f, ay = 0.f;
    for (int i = beg; i < end; ++i) {
        int s = csr[i];
        float2 v = *(const float2*)(act + (size_t)s * D + lane * 2);
        ax += v.x; ay += v.y;
    }
    int deg = end - beg;
    float inv = 1.0f / (float)(deg > 1 ? deg : 1);
    float2 o; o.x = ax * inv; o.y = ay * inv;
    *(float2*)(mean + (size_t)wid * D + lane * 2) = o;
}

// ---------------------------------------------------------------------------
// fused dual GEMM: out[n,:] = mean[n,:] @ Wl + act[n,:] @ Wr + bias (+ReLU)
// K = 256 stacked. 64 nodes x 128 cols per block, 8x4 micro-tile per thread.
// LDS: in_tile 64KB + w_tile 16KB = 80KB -> 2 blocks/CU.
// Safe for out == act (row n read into LDS before any store of row n; output
// row depends only on input row n, and rows are block-exclusive).
__global__ __launch_bounds__(256) void sage_gemm(
        const float* __restrict__ mean, const float* __restrict__ act,
        const float* __restrict__ Wl, const float* __restrict__ Wr,
        const float* __restrict__ bias, float* __restrict__ out,
        int n, int relu) {
    __shared__ float in_tile[TN][KK];   // 64 x 256 f32 = 64KB
    __shared__ float w_tile[32][D];     // 32 x 128 f32 = 16KB
    int tid = threadIdx.x;
    int node0 = blockIdx.x * TN;

    // stage input tile: [mean row | act row] as float4 (coalesced)
    for (int f = tid; f < TN * KK / 4; f += 256) {
        int row = f >> 6;       // 64 float4 per row
        int o4  = f & 63;
        int node = node0 + row;
        float4 v = make_float4(0.f, 0.f, 0.f, 0.f);
        if (node < n) {
            if (o4 < 32) v = *(const float4*)(mean + (size_t)node * D + o4 * 4);
            else         v = *(const float4*)(act  + (size_t)node * D + (o4 - 32) * 4);
        }
        *(float4*)&in_tile[row][o4 * 4] = v;
    }

    int cg = tid & 31;   // cols cg + {0,32,64,96}
    int ng = tid >> 5;   // nodes ng*8 + i
    float acc[8][4];
    #pragma unroll
    for (int i = 0; i < 8; ++i)
        #pragma unroll
        for (int j = 0; j < 4; ++j) acc[i][j] = 0.f;

    for (int kt = 0; kt < KK; kt += 32) {
        __syncthreads();   // in_tile ready (iter 0) / previous compute done
        // stage W chunk rows kt..kt+31 of stacked [Wl; Wr]
        for (int f = tid; f < 32 * D / 4; f += 256) {
            int r  = f >> 5;       // 32 float4 per row
            int o4 = f & 31;
            int k  = kt + r;
            const float* wsrc = (k < D) ? (Wl + (size_t)k * D)
                                        : (Wr + (size_t)(k - D) * D);
            *(float4*)&w_tile[r][o4 * 4] = *(const float4*)(wsrc + o4 * 4);
        }
        __syncthreads();

        #pragma unroll
        for (int k4 = 0; k4 < 32; k4 += 4) {
            float4 a4[8];
            #pragma unroll
            for (int i = 0; i < 8; ++i)
                a4[i] = *(const float4*)&in_tile[ng * 8 + i][kt + k4];
            #pragma unroll
            for (int u = 0; u < 4; ++u) {
                float b0 = w_tile[k4 + u][cg];
                float b1 = w_tile[k4 + u][cg + 32];
                float b2 = w_tile[k4 + u][cg + 64];
                float b3 = w_tile[k4 + u][cg + 96];
                #pragma unroll
                for (int i = 0; i < 8; ++i) {
                    float a = ((const float*)&a4[i])[u];
                    acc[i][0] += a * b0;
                    acc[i][1] += a * b1;
                    acc[i][2] += a * b2;
                    acc[i][3] += a * b3;
                }
            }
        }
    }

    float b0 = bias[cg], b1 = bias[cg + 32], b2 = bias[cg + 64], b3 = bias[cg + 96];
    #pragma unroll
    for (int i = 0; i < 8; ++i) {
        int node = node0 + ng * 8 + i;
        if (node >= n) break;
        float v0 = acc[i][0] + b0;
        float v1 = acc[i][1] + b1;
        float v2 = acc[i][2] + b2;
        float v3 = acc[i][3] + b3;
        if (relu) {
            v0 = fmaxf(v0, 0.f); v1 = fmaxf(v1, 0.f);
            v2 = fmaxf(v2, 0.f); v3 = fmaxf(v3, 0.f);
        }
        float* o = out + (size_t)node * D;
        o[cg]      = v0;
        o[cg + 32] = v1;
        o[cg + 64] = v2;
        o[cg + 96] = v3;
    }
}

// ---------------------------------------------------------------------------
extern "C" void kernel_launch(void* const* d_in, const int* in_sizes, int n_in,
                              void* d_out, int out_size, void* d_ws, size_t ws_size,
                              hipStream_t stream) {
    const float* x  = (const float*)d_in[0];
    const void*  ei = d_in[1];
    const float* Wa = (const float*)d_in[2];   // [3,128,128]
    const float* Wr = (const float*)d_in[3];   // [3,128,128]
    const float* bb = (const float*)d_in[4];   // [3,128]
    float* outp = (float*)d_out;

    int n  = in_sizes[0] / D;          // 100000
    int nE = in_sizes[1] / 2;          // 1600000

    // workspace layout
    char* ws = (char*)d_ws;
    size_t off = 0;
    auto alloc = [&](size_t bytes) -> char* {
        char* p = ws + off;
        off = (off + bytes + 255) & ~(size_t)255;
        return p;
    };
    int* flag      = (int*)alloc(4);
    int* src32     = (int*)alloc((size_t)nE * 4);
    int* dst32     = (int*)alloc((size_t)nE * 4);
    int* counts    = (int*)alloc((size_t)n * 4);
    int* offsets   = (int*)alloc(((size_t)n + 1) * 4);
    int* cursor    = (int*)alloc((size_t)n * 4);
    int* local_inc = (int*)alloc((size_t)n * 4);
    int* bsums     = (int*)alloc(1024);
    int* csr_src   = (int*)alloc((size_t)nE * 4);
    float* meanA   = (float*)alloc((size_t)n * D * 4);
    float* actB    = (float*)alloc((size_t)n * D * 4);
    (void)ws_size; (void)n_in; (void)out_size;

    const int B = 256;
    int ge = (nE + B - 1) / B;
    int nb = (n + 1023) / 1024;

    // 1) index dtype probe + conversion
    hipLaunchKernelGGL(detect_idx, dim3(1), dim3(64), 0, stream, ei, flag, n);
    hipLaunchKernelGGL(convert_idx, dim3(ge), dim3(B), 0, stream,
                       ei, flag, src32, dst32, nE);

    // 2) CSR build (once, reused for all 3 layers)
    hipMemsetAsync(counts, 0, (size_t)n * 4, stream);
    hipMemsetAsync(cursor, 0, (size_t)n * 4, stream);
    hipLaunchKernelGGL(hist_kernel, dim3(ge), dim3(B), 0, stream, dst32, counts, nE);
    hipLaunchKernelGGL(scan1, dim3(nb), dim3(1024), 0, stream,
                       counts, local_inc, bsums, n);
    hipLaunchKernelGGL(scan2, dim3(1), dim3(64), 0, stream, bsums, nb);
    hipLaunchKernelGGL(scan3, dim3((n + B - 1) / B), dim3(B), 0, stream,
                       local_inc, counts, bsums, offsets, n, nE);
    hipLaunchKernelGGL(fill_csr, dim3(ge), dim3(B), 0, stream,
                       src32, dst32, offsets, cursor, csr_src, nE);

    // 3) layers
    int agg_blocks  = (n * 64 + B - 1) / B;       // one wave per node
    int gemm_blocks = (n + TN - 1) / TN;

    // layer 0: x -> actB (ReLU)
    hipLaunchKernelGGL(agg_mean, dim3(agg_blocks), dim3(B), 0, stream,
                       x, csr_src, offsets, meanA, n);
    hipLaunchKernelGGL(sage_gemm, dim3(gemm_blocks), dim3(B), 0, stream,
                       meanA, x, Wa + 0 * D * D, Wr + 0 * D * D, bb + 0 * D,
                       actB, n, 1);

    // layer 1: actB -> actB in-place (ReLU)
    hipLaunchKernelGGL(agg_mean, dim3(agg_blocks), dim3(B), 0, stream,
                       actB, csr_src, offsets, meanA, n);
    hipLaunchKernelGGL(sage_gemm, dim3(gemm_blocks), dim3(B), 0, stream,
                       meanA, actB, Wa + 1 * D * D, Wr + 1 * D * D, bb + 1 * D,
                       actB, n, 1);

    // layer 2: actB -> d_out (no ReLU)
    hipLaunchKernelGGL(agg_mean, dim3(agg_blocks), dim3(B), 0, stream,
                       actB, csr_src, offsets, meanA, n);
    hipLaunchKernelGGL(sage_gemm, dim3(gemm_blocks), dim3(B), 0, stream,
                       meanA, actB, Wa + 2 * D * D, Wr + 2 * D * D, bb + 2 * D,
                       outp, n, 0);
}

// Round 2
// 698.836 us; speedup vs baseline: 1.5654x; 1.5654x over previous
//
#include <hip/hip_runtime.h>
#include <stdint.h>

#define D 128
#define TN 64
#define PADK 40   // 32-k chunk padded to 40 bf16 (80 B row stride: 16B-aligned, 2-way banks)

typedef __attribute__((ext_vector_type(8))) __bf16 bf16x8;
typedef __attribute__((ext_vector_type(4))) float f32x4;

// ---------------------------------------------------------------------------
// edge_index dtype detection (int64 per reference vs int32 from x64-disabled JAX)
__global__ void detect_idx(const void* ei, int* flag, int n_nodes) {
    if (blockIdx.x == 0 && threadIdx.x == 0) {
        const long long* p = (const long long*)ei;
        int is64 = 1;
        for (int i = 0; i < 64; ++i) {
            long long v = p[i];
            if (v < 0 || v >= (long long)n_nodes) { is64 = 0; break; }
        }
        *flag = is64;
    }
}

__global__ void convert_idx(const void* ei, const int* flag,
                            int* src32, int* dst32, int nE) {
    int e = blockIdx.x * blockDim.x + threadIdx.x;
    if (e >= nE) return;
    if (*flag) {
        const long long* p = (const long long*)ei;
        src32[e] = (int)p[e];
        dst32[e] = (int)p[(size_t)nE + e];
    } else {
        const int* p = (const int*)ei;
        src32[e] = p[e];
        dst32[e] = p[nE + e];
    }
}

// ---------------------------------------------------------------------------
// CSR build (by dst), reused across all 3 layers
__global__ void hist_kernel(const int* dst32, int* counts, int nE) {
    int e = blockIdx.x * blockDim.x + threadIdx.x;
    if (e < nE) atomicAdd(&counts[dst32[e]], 1);
}

__global__ void scan1(const int* counts, int* local_inc, int* bsums, int n) {
    __shared__ int s[1024];
    int i = blockIdx.x * 1024 + threadIdx.x;
    int v = (i < n) ? counts[i] : 0;
    s[threadIdx.x] = v;
    __syncthreads();
    for (int off = 1; off < 1024; off <<= 1) {
        int t = 0;
        if ((int)threadIdx.x >= off) t = s[threadIdx.x - off];
        __syncthreads();
        if ((int)threadIdx.x >= off) s[threadIdx.x] += t;
        __syncthreads();
    }
    if (i < n) local_inc[i] = s[threadIdx.x];
    if (threadIdx.x == 1023) bsums[blockIdx.x] = s[1023];
}

__global__ void scan2(int* bsums, int nb) {
    if (blockIdx.x == 0 && threadIdx.x == 0) {
        int run = 0;
        for (int i = 0; i < nb; ++i) { int v = bsums[i]; bsums[i] = run; run += v; }
    }
}

__global__ void scan3(const int* local_inc, const int* counts, const int* bsums,
                      int* offsets, int n, int nE) {
    int i = blockIdx.x * blockDim.x + threadIdx.x;
    if (i < n) offsets[i] = local_inc[i] - counts[i] + bsums[i >> 10];
    if (i == 0) offsets[n] = nE;
}

__global__ void fill_csr(const int* src32, const int* dst32, const int* offsets,
                         int* cursor, int* csr_src, int nE) {
    int e = blockIdx.x * blockDim.x + threadIdx.x;
    if (e < nE) {
        int d = dst32[e];
        int pos = offsets[d] + atomicAdd(&cursor[d], 1);
        csr_src[pos] = src32[e];
    }
}

// ---------------------------------------------------------------------------
// W preprocessing: stacked [Wl;Wr] transposed to [col][k] and split to bf16 hi/lo.
// Wt[L][c][k], k<128 -> W_agg[L][k][c], k>=128 -> W_root[L][k-128][c].
__global__ void build_wt(const float* __restrict__ Wa, const float* __restrict__ Wr,
                         __bf16* __restrict__ WtHi, __bf16* __restrict__ WtLo) {
    int idx = blockIdx.x * 256 + threadIdx.x;         // 3*128*256 total
    if (idx >= 3 * 128 * 256) return;
    int L = idx / (128 * 256);
    int rem = idx % (128 * 256);
    int c = rem / 256;
    int k = rem % 256;
    float v = (k < 128) ? Wa[((size_t)L * 128 + k) * 128 + c]
                        : Wr[((size_t)L * 128 + (k - 128)) * 128 + c];
    __bf16 h = (__bf16)v;
    __bf16 l = (__bf16)(v - (float)h);
    WtHi[idx] = h;
    WtLo[idx] = l;
}

// ---------------------------------------------------------------------------
// mean aggregation v2: one node per 32-lane half-wave, float4/lane, 4x unroll
// for memory-level parallelism (4 independent 512B row-gathers in flight).
__global__ __launch_bounds__(256) void agg_mean2(
        const float* __restrict__ act, const int* __restrict__ csr,
        const int* __restrict__ offs, float* __restrict__ mean, int n) {
    int half = (blockIdx.x * blockDim.x + threadIdx.x) >> 5;
    int c = (threadIdx.x & 31) << 2;       // float offset of this lane's float4
    if (half >= n) return;
    int beg = offs[half], end = offs[half + 1];
    float ax = 0.f, ay = 0.f, az = 0.f, aw = 0.f;
    int i = beg;
    for (; i + 4 <= end; i += 4) {
        int s0 = csr[i], s1 = csr[i + 1], s2 = csr[i + 2], s3 = csr[i + 3];
        float4 v0 = *(const float4*)(act + (size_t)s0 * D + c);
        float4 v1 = *(const float4*)(act + (size_t)s1 * D + c);
        float4 v2 = *(const float4*)(act + (size_t)s2 * D + c);
        float4 v3 = *(const float4*)(act + (size_t)s3 * D + c);
        ax += v0.x + v1.x + v2.x + v3.x;
        ay += v0.y + v1.y + v2.y + v3.y;
        az += v0.z + v1.z + v2.z + v3.z;
        aw += v0.w + v1.w + v2.w + v3.w;
    }
    for (; i < end; ++i) {
        int s = csr[i];
        float4 v = *(const float4*)(act + (size_t)s * D + c);
        ax += v.x; ay += v.y; az += v.z; aw += v.w;
    }
    int deg = end - beg;
    float inv = 1.0f / (float)(deg > 1 ? deg : 1);
    float4 o; o.x = ax * inv; o.y = ay * inv; o.z = az * inv; o.w = aw * inv;
    *(float4*)(mean + (size_t)half * D + c) = o;
}

// ---------------------------------------------------------------------------
// MFMA GEMM with bf16 hi/lo split (fp32-accurate): out = [mean|act] @ [Wl;Wr] + b.
// Tile 64 nodes x 128 cols, K=256 in 32-chunks. 4 waves, wave w = rows w*16..+16.
// acc += hi*hi + hi*lo + lo*hi (lo*lo ~2^-32, dropped). LDS ~30KB -> 5 blocks/CU.
__global__ __launch_bounds__(256) void sage_gemm2(
        const float* __restrict__ mean, const float* __restrict__ act,
        const __bf16* __restrict__ WtHi, const __bf16* __restrict__ WtLo,
        const float* __restrict__ bias, float* __restrict__ out,
        int n, int relu) {
    __shared__ __bf16 Ah[TN][PADK], Al[TN][PADK];     // 5 KB each
    __shared__ __bf16 Bh[D][PADK],  Bl[D][PADK];      // 10 KB each
    int tid   = threadIdx.x;
    int wave  = tid >> 6;
    int lane  = tid & 63;
    int row16 = lane & 15;
    int kg    = lane >> 4;        // k-group: lane holds k = kg*8 + 0..7
    int node0 = blockIdx.x * TN;

    f32x4 acc[8];
    #pragma unroll
    for (int nt = 0; nt < 8; ++nt) acc[nt] = (f32x4){0.f, 0.f, 0.f, 0.f};

    for (int kt = 0; kt < 256; kt += 32) {
        __syncthreads();
        // ---- stage A chunk: 64 rows x 32 k (mean for kt<128 else act), cvt->hi/lo
        for (int f = tid; f < 512; f += 256) {          // 512 float4
            int r  = f >> 3;                            // 8 float4 per row
            int c4 = f & 7;
            int node = node0 + r;
            float4 v = make_float4(0.f, 0.f, 0.f, 0.f);
            int gc = kt + c4 * 4;
            if (node < n) {
                const float* src = (gc < D) ? (mean + (size_t)node * D + gc)
                                            : (act  + (size_t)node * D + gc - D);
                v = *(const float4*)src;
            }
            union { __bf16 b[4]; short4 s; } uh, ul;
            float vv[4] = {v.x, v.y, v.z, v.w};
            #pragma unroll
            for (int j = 0; j < 4; ++j) {
                uh.b[j] = (__bf16)vv[j];
                ul.b[j] = (__bf16)(vv[j] - (float)uh.b[j]);
            }
            *(short4*)&Ah[r][c4 * 4] = uh.s;
            *(short4*)&Al[r][c4 * 4] = ul.s;
        }
        // ---- stage W chunk: 128 cols x 32 k from pre-transposed hi/lo
        for (int f = tid; f < 1024; f += 256) {         // 1024 short4 per array
            int cc = f >> 3;
            int c4 = f & 7;
            *(short4*)&Bh[cc][c4 * 4] =
                *(const short4*)(WtHi + (size_t)cc * 256 + kt + c4 * 4);
            *(short4*)&Bl[cc][c4 * 4] =
                *(const short4*)(WtLo + (size_t)cc * 256 + kt + c4 * 4);
        }
        __syncthreads();

        // ---- fragments + MFMA
        int arow = wave * 16 + row16;
        bf16x8 ahf = *(const bf16x8*)&Ah[arow][kg * 8];
        bf16x8 alf = *(const bf16x8*)&Al[arow][kg * 8];
        #pragma unroll
        for (int nt = 0; nt < 8; ++nt) {
            int bcol = nt * 16 + row16;
            bf16x8 bhf = *(const bf16x8*)&Bh[bcol][kg * 8];
            bf16x8 blf = *(const bf16x8*)&Bl[bcol][kg * 8];
            acc[nt] = __builtin_amdgcn_mfma_f32_16x16x32_bf16(ahf, bhf, acc[nt], 0, 0, 0);
            acc[nt] = __builtin_amdgcn_mfma_f32_16x16x32_bf16(ahf, blf, acc[nt], 0, 0, 0);
            acc[nt] = __builtin_amdgcn_mfma_f32_16x16x32_bf16(alf, bhf, acc[nt], 0, 0, 0);
        }
    }

    // ---- epilogue: C/D layout col=lane&15, row=(lane>>4)*4+reg (m89-verified)
    #pragma unroll
    for (int nt = 0; nt < 8; ++nt) {
        float bv = bias[nt * 16 + row16];
        #pragma unroll
        for (int j = 0; j < 4; ++j) {
            int node = node0 + wave * 16 + kg * 4 + j;
            if (node < n) {
                float val = acc[nt][j] + bv;
                if (relu) val = fmaxf(val, 0.f);
                out[(size_t)node * D + nt * 16 + row16] = val;
            }
        }
    }
}

// ---------------------------------------------------------------------------
extern "C" void kernel_launch(void* const* d_in, const int* in_sizes, int n_in,
                              void* d_out, int out_size, void* d_ws, size_t ws_size,
                              hipStream_t stream) {
    const float* x  = (const float*)d_in[0];
    const void*  ei = d_in[1];
    const float* Wa = (const float*)d_in[2];   // [3,128,128]
    const float* Wr = (const float*)d_in[3];   // [3,128,128]
    const float* bb = (const float*)d_in[4];   // [3,128]
    float* outp = (float*)d_out;

    int n  = in_sizes[0] / D;          // 100000
    int nE = in_sizes[1] / 2;          // 1600000

    char* ws = (char*)d_ws;
    size_t off = 0;
    auto alloc = [&](size_t bytes) -> char* {
        char* p = ws + off;
        off = (off + bytes + 255) & ~(size_t)255;
        return p;
    };
    int* flag      = (int*)alloc(4);
    int* src32     = (int*)alloc((size_t)nE * 4);
    int* dst32     = (int*)alloc((size_t)nE * 4);
    int* counts    = (int*)alloc((size_t)n * 4);
    int* offsets   = (int*)alloc(((size_t)n + 1) * 4);
    int* cursor    = (int*)alloc((size_t)n * 4);
    int* local_inc = (int*)alloc((size_t)n * 4);
    int* bsums     = (int*)alloc(1024);
    int* csr_src   = (int*)alloc((size_t)nE * 4);
    float* meanA   = (float*)alloc((size_t)n * D * 4);
    float* actB    = (float*)alloc((size_t)n * D * 4);
    __bf16* WtHi   = (__bf16*)alloc((size_t)3 * 128 * 256 * 2);
    __bf16* WtLo   = (__bf16*)alloc((size_t)3 * 128 * 256 * 2);
    (void)ws_size; (void)n_in; (void)out_size;

    const int B = 256;
    int ge = (nE + B - 1) / B;
    int nb = (n + 1023) / 1024;

    // 1) index dtype probe + conversion + W preprocessing
    hipLaunchKernelGGL(detect_idx, dim3(1), dim3(64), 0, stream, ei, flag, n);
    hipLaunchKernelGGL(convert_idx, dim3(ge), dim3(B), 0, stream,
                       ei, flag, src32, dst32, nE);
    hipLaunchKernelGGL(build_wt, dim3(384), dim3(256), 0, stream, Wa, Wr, WtHi, WtLo);

    // 2) CSR build
    hipMemsetAsync(counts, 0, (size_t)n * 4, stream);
    hipMemsetAsync(cursor, 0, (size_t)n * 4, stream);
    hipLaunchKernelGGL(hist_kernel, dim3(ge), dim3(B), 0, stream, dst32, counts, nE);
    hipLaunchKernelGGL(scan1, dim3(nb), dim3(1024), 0, stream,
                       counts, local_inc, bsums, n);
    hipLaunchKernelGGL(scan2, dim3(1), dim3(64), 0, stream, bsums, nb);
    hipLaunchKernelGGL(scan3, dim3((n + B - 1) / B), dim3(B), 0, stream,
                       local_inc, counts, bsums, offsets, n, nE);
    hipLaunchKernelGGL(fill_csr, dim3(ge), dim3(B), 0, stream,
                       src32, dst32, offsets, cursor, csr_src, nE);

    // 3) layers
    int agg_blocks  = ((n + 7) / 8);               // 8 nodes per 256-thread block
    int gemm_blocks = (n + TN - 1) / TN;
    const int WSTRIDE = 128 * 256;

    // layer 0: x -> actB (ReLU)
    hipLaunchKernelGGL(agg_mean2, dim3(agg_blocks), dim3(B), 0, stream,
                       x, csr_src, offsets, meanA, n);
    hipLaunchKernelGGL(sage_gemm2, dim3(gemm_blocks), dim3(B), 0, stream,
                       meanA, x, WtHi + 0 * WSTRIDE, WtLo + 0 * WSTRIDE,
                       bb + 0 * D, actB, n, 1);

    // layer 1: actB -> actB (in-place safe: block-exclusive rows) (ReLU)
    hipLaunchKernelGGL(agg_mean2, dim3(agg_blocks), dim3(B), 0, stream,
                       actB, csr_src, offsets, meanA, n);
    hipLaunchKernelGGL(sage_gemm2, dim3(gemm_blocks), dim3(B), 0, stream,
                       meanA, actB, WtHi + 1 * WSTRIDE, WtLo + 1 * WSTRIDE,
                       bb + 1 * D, actB, n, 1);

    // layer 2: actB -> d_out (no ReLU)
    hipLaunchKernelGGL(agg_mean2, dim3(agg_blocks), dim3(B), 0, stream,
                       actB, csr_src, offsets, meanA, n);
    hipLaunchKernelGGL(sage_gemm2, dim3(gemm_blocks), dim3(B), 0, stream,
                       meanA, actB, WtHi + 2 * WSTRIDE, WtLo + 2 * WSTRIDE,
                       bb + 2 * D, outp, n, 0);
}